// Round 6
// baseline (899.670 us; speedup 1.0000x reference)
//
#include <hip/hip_runtime.h>
#include <hip/hip_bf16.h>
#include <stdint.h>

typedef float f32x2 __attribute__((ext_vector_type(2)));
typedef float f32x4 __attribute__((ext_vector_type(4)));
typedef short s16x8 __attribute__((ext_vector_type(8)));

#define CUBIC_A (-0.75f)
#define S3 262144.0f   // 2^18 scale for plane3
#define S2 131072.0f   // 2^17 scale for plane2
#define SV 32768.0f    // 2^15 scale for vec

#define SB() __builtin_amdgcn_sched_barrier(0)

__device__ __forceinline__ void axis_taps(float c, int size, float* w, int* idx) {
  float ix = (c + 1.0f) * 0.5f * (float)(size - 1);
  float x0f = floorf(ix);
  float t = ix - x0f;
  float s = t + 1.0f;
  w[0] = ((CUBIC_A * s - 5.0f * CUBIC_A) * s + 8.0f * CUBIC_A) * s - 4.0f * CUBIC_A;
  w[1] = ((CUBIC_A + 2.0f) * t - (CUBIC_A + 3.0f)) * t * t + 1.0f;
  float u = 1.0f - t;
  w[2] = ((CUBIC_A + 2.0f) * u - (CUBIC_A + 3.0f)) * u * u + 1.0f;
  float v = 2.0f - t;
  w[3] = ((CUBIC_A * v - 5.0f * CUBIC_A) * v + 8.0f * CUBIC_A) * v - 4.0f * CUBIC_A;
  int x0 = (int)x0f;
#pragma unroll
  for (int k = 0; k < 4; ++k) {
    int qq = x0 - 1 + k;
    qq = qq < 0 ? 0 : qq;
    qq = qq > size - 1 ? size - 1 : qq;
    idx[k] = qq;
  }
}

// issue 16 tap loads (8 channels each) into r[16]
__device__ __forceinline__ void issueP(const uint8_t* __restrict__ base,
                                       const int* ro, const int* co, uint2* r) {
#pragma unroll
  for (int i = 0; i < 4; ++i)
#pragma unroll
    for (int j = 0; j < 4; ++j)
      r[i * 4 + j] = *reinterpret_cast<const uint2*>(base + ro[i] + co[j]);
}

__device__ __forceinline__ void consume_tap(uint2 uv, float w, f32x2* acc) {
  f32x2 w2; w2.x = w; w2.y = w;
  acc[0] += w2 * __builtin_amdgcn_cvt_pk_f32_fp8((int)uv.x, false);
  acc[1] += w2 * __builtin_amdgcn_cvt_pk_f32_fp8((int)uv.x, true);
  acc[2] += w2 * __builtin_amdgcn_cvt_pk_f32_fp8((int)uv.y, false);
  acc[3] += w2 * __builtin_amdgcn_cvt_pk_f32_fp8((int)uv.y, true);
}

__device__ __forceinline__ void consumeP(const float* wr, const float* wc,
                                         const uint2* r, f32x2* acc) {
#pragma unroll
  for (int i = 0; i < 4; ++i)
#pragma unroll
    for (int j = 0; j < 4; ++j)
      consume_tap(r[i * 4 + j], wr[i] * wc[j], acc);
}

// ---------------- prep kernels ----------------

__device__ __forceinline__ float comb_row(const float* __restrict__ B, int r, int j) {
  return (r < 32) ? (B[r * 64 + j] + B[(r + 32) * 64 + j]) : B[(r + 32) * 64 + j];
}

__device__ __forceinline__ uint32_t pack_bf16(float v0, float v1) {
  uint32_t a = __float_as_uint(v0);
  uint32_t b = __float_as_uint(v1);
  uint32_t r0 = (a + 0x7fffu + ((a >> 16) & 1u)) >> 16;     // RNE
  uint32_t r1 = (b + 0x7fffu + ((b >> 16) & 1u)) >> 16;
  return (r0 & 0xffffu) | (r1 << 16);
}

// Bf[seg=3][cb=4][lane=64] = uint4 (8 bf16, k=(lane>>4)*8+e, j=cb*16+(lane&15)), invS folded
__global__ void __launch_bounds__(256) make_bfrag(const float* __restrict__ B, uint4* __restrict__ Bf) {
  int i = blockIdx.x * 256 + threadIdx.x;
  if (i >= 768) return;
  int lane = i & 63;
  int cb = (i >> 6) & 3;
  int seg = i >> 8;
  float invS = (seg == 0) ? (1.0f / S3) : (seg == 1) ? (1.0f / S2) : (1.0f / SV);
  int j = cb * 16 + (lane & 15);
  int h = lane >> 4;
  uint32_t o[4];
#pragma unroll
  for (int r = 0; r < 4; ++r) {
    int k0 = seg * 32 + h * 8 + 2 * r;
    float v0 = comb_row(B, k0, j) * invS;
    float v1 = comb_row(B, k0 + 1, j) * invS;
    o[r] = pack_bf16(v0, v1);
  }
  uint4 st; st.x = o[0]; st.y = o[1]; st.z = o[2]; st.w = o[3];
  Bf[(seg * 4 + cb) * 64 + lane] = st;
}

// Transpose+quantize (P, 32, H, W) fp32 -> (P, H, W, 32) fp8 e4m3 scaled by S.
__global__ void __launch_bounds__(256) transpose_cl8(const float* __restrict__ in,
                                                     uint8_t* __restrict__ out,
                                                     int H, int W, int nxt, float S) {
  __shared__ float tile[32][65];
  int b = blockIdx.x;
  int xt = b % nxt;
  int tmp = b / nxt;
  int y = tmp % H;
  int p = tmp / H;
  int x0 = xt * 64;
  int lane = threadIdx.x;
  const float* src = in + ((size_t)p * 32 * (size_t)H) * (size_t)W + (size_t)y * (size_t)W;
  int cx = lane & 63;
  int c4 = lane >> 6;
#pragma unroll
  for (int pass = 0; pass < 8; ++pass) {
    int c = pass * 4 + c4;
    tile[c][cx] = src[(size_t)c * (size_t)(H) * (size_t)W + x0 + cx];
  }
  __syncthreads();
  int xx = lane >> 2;
  int c8 = (lane & 3) * 8;
  float f[8];
#pragma unroll
  for (int i = 0; i < 8; ++i) f[i] = tile[c8 + i][xx] * S;
  uint32_t lo = 0, hi = 0;
  lo = (uint32_t)__builtin_amdgcn_cvt_pk_fp8_f32(f[0], f[1], (int)lo, false);
  lo = (uint32_t)__builtin_amdgcn_cvt_pk_fp8_f32(f[2], f[3], (int)lo, true);
  hi = (uint32_t)__builtin_amdgcn_cvt_pk_fp8_f32(f[4], f[5], (int)hi, false);
  hi = (uint32_t)__builtin_amdgcn_cvt_pk_fp8_f32(f[6], f[7], (int)hi, true);
  uint8_t* dst = out + (((size_t)p * H + y) * (size_t)W + x0 + xx) * 32 + c8;
  uint2 st; st.x = lo; st.y = hi;
  *reinterpret_cast<uint2*>(dst) = st;
}

// ---------------- main kernel: sched_barrier-pinned pipelined fp8 gather, MFMA projection ----------------

__global__ void __launch_bounds__(256, 4) triplane_main(
    const float* __restrict__ coords,
    const uint8_t* __restrict__ p3t,   // (3,128,128,32) fp8
    const uint8_t* __restrict__ p2t,   // (3,256,256,32) fp8
    const uint8_t* __restrict__ vt,    // (3,512,32) fp8
    const uint4* __restrict__ Bfrag,   // [3][4][64] uint4
    float* __restrict__ out, int N) {
  int t = blockIdx.x * 256 + threadIdx.x;
  int l = threadIdx.x & 63;
  int n0 = (blockIdx.x * 256 + (threadIdx.x & ~63)) >> 2;  // first point of this wave
  if (n0 >= N) return;
  int n = t >> 2;
  int q = t & 3;

  float x = coords[3 * n + 0];
  float y = coords[3 * n + 1];
  float z = coords[3 * n + 2];

  f32x2 feat2[12];
#pragma unroll
  for (int i = 0; i < 12; ++i) { feat2[i].x = 0.f; feat2[i].y = 0.f; }

  const int qo = q * 8;
  uint2 rA[16], rB[16];
  float wx[4], wy[4], wz[4];
  int ti[4];
  int oxc[4], oyr[4], oyc[4], ozr[4];

  // ======== scale 3 (128x128) ========
  axis_taps(x, 128, wx, ti);
#pragma unroll
  for (int k = 0; k < 4; ++k) oxc[k] = ti[k] * 32;
  axis_taps(y, 128, wy, ti);
#pragma unroll
  for (int k = 0; k < 4; ++k) { oyr[k] = ti[k] * 128 * 32; oyc[k] = ti[k] * 32; }
  axis_taps(z, 128, wz, ti);
#pragma unroll
  for (int k = 0; k < 4; ++k) ozr[k] = ti[k] * 128 * 32;

  issueP(p3t + qo,                      oyr, oxc, rA);   // xy: rows y, cols x
  issueP(p3t + 1 * 128 * 128 * 32 + qo, ozr, oyc, rB);   // yz: rows z, cols y
  SB();
  consumeP(wy, wx, rA, feat2 + 0);
  issueP(p3t + 2 * 128 * 128 * 32 + qo, ozr, oxc, rA);   // xz: rows z, cols x
  SB();

  // ======== scale 2 taps (compute while xz in flight) ========
  float wx2[4], wy2[4], wz2[4];
  int oxc2[4], oyr2[4], oyc2[4], ozr2[4];
  axis_taps(x, 256, wx2, ti);
#pragma unroll
  for (int k = 0; k < 4; ++k) oxc2[k] = ti[k] * 32;
  axis_taps(y, 256, wy2, ti);
#pragma unroll
  for (int k = 0; k < 4; ++k) { oyr2[k] = ti[k] * 256 * 32; oyc2[k] = ti[k] * 32; }
  axis_taps(z, 256, wz2, ti);
#pragma unroll
  for (int k = 0; k < 4; ++k) ozr2[k] = ti[k] * 256 * 32;

  consumeP(wz, wy, rB, feat2 + 0);                       // p3 yz
  issueP(p2t + qo, oyr2, oxc2, rB);                      // p2 xy
  SB();
  consumeP(wz, wx, rA, feat2 + 0);                       // p3 xz
  issueP(p2t + 1 * 256 * 256 * 32 + qo, ozr2, oyc2, rA); // p2 yz
  SB();
  consumeP(wy2, wx2, rB, feat2 + 4);                     // p2 xy
  issueP(p2t + 2 * 256 * 256 * 32 + qo, ozr2, oxc2, rB); // p2 xz
  SB();

  // ======== vector taps ========
  float wvx[4], wvy[4], wvz[4];
  int ovx[4], ovy[4], ovz[4];
  axis_taps(x, 512, wvx, ti);
#pragma unroll
  for (int k = 0; k < 4; ++k) ovx[k] = ti[k] * 32;
  axis_taps(y, 512, wvy, ti);
#pragma unroll
  for (int k = 0; k < 4; ++k) ovy[k] = ti[k] * 32;
  axis_taps(z, 512, wvz, ti);
#pragma unroll
  for (int k = 0; k < 4; ++k) ovz[k] = ti[k] * 32;

  consumeP(wz2, wy2, rA, feat2 + 4);                     // p2 yz
  {
    const uint8_t* v0 = vt + qo;
    const uint8_t* v1 = vt + 1 * 512 * 32 + qo;
    const uint8_t* v2 = vt + 2 * 512 * 32 + qo;
#pragma unroll
    for (int i = 0; i < 4; ++i) {
      rA[i]     = *reinterpret_cast<const uint2*>(v0 + ovx[i]);
      rA[4 + i] = *reinterpret_cast<const uint2*>(v1 + ovy[i]);
      rA[8 + i] = *reinterpret_cast<const uint2*>(v2 + ovz[i]);
    }
  }
  SB();
  consumeP(wz2, wx2, rB, feat2 + 4);                     // p2 xz
  SB();
#pragma unroll
  for (int i = 0; i < 4; ++i) {
    consume_tap(rA[i],     wvx[i], feat2 + 8);
    consume_tap(rA[4 + i], wvy[i], feat2 + 8);
    consume_tap(rA[8 + i], wvz[i], feat2 + 8);
  }

  // ---- pack feat to bf16 pairs (12 dwords) ----
  uint32_t packed[12];
#pragma unroll
  for (int i = 0; i < 12; ++i) {
    uint32_t r;
    asm("v_cvt_pk_bf16_f32 %0, %1, %2" : "=v"(r) : "v"(feat2[i].x), "v"(feat2[i].y));
    packed[i] = r;
  }

  // ---- redistribute to MFMA A-fragment layout: lane 16h+p pulls from lane 4p+h ----
  int baddr = (4 * (l & 15) + (l >> 4)) * 4;
  uint32_t apk[12];
#pragma unroll
  for (int i = 0; i < 12; ++i)
    apk[i] = (uint32_t)__builtin_amdgcn_ds_bpermute(baddr, (int)packed[i]);

  // ---- load B fragments ----
  uint4 bfr[12];
#pragma unroll
  for (int i = 0; i < 12; ++i) bfr[i] = Bfrag[i * 64 + l];

  // ---- 12 MFMAs ----
  union U { uint32_t u[4]; s16x8 v; };
  f32x4 acc[4];
#pragma unroll
  for (int cb = 0; cb < 4; ++cb) { acc[cb].x = 0.f; acc[cb].y = 0.f; acc[cb].z = 0.f; acc[cb].w = 0.f; }
#pragma unroll
  for (int seg = 0; seg < 3; ++seg) {
    U a;
    a.u[0] = apk[seg * 4 + 0];
    a.u[1] = apk[seg * 4 + 1];
    a.u[2] = apk[seg * 4 + 2];
    a.u[3] = apk[seg * 4 + 3];
#pragma unroll
    for (int cb = 0; cb < 4; ++cb) {
      U b;
      b.u[0] = bfr[seg * 4 + cb].x;
      b.u[1] = bfr[seg * 4 + cb].y;
      b.u[2] = bfr[seg * 4 + cb].z;
      b.u[3] = bfr[seg * 4 + cb].w;
      acc[cb] = __builtin_amdgcn_mfma_f32_16x16x32_bf16(a.v, b.v, acc[cb], 0, 0, 0);
    }
  }

  // ---- epilogue: sin/cos + store. C/D: row (=point) = (l>>4)*4+reg, col = l&15 ----
  int h = l >> 4;
  int jc = l & 15;
#pragma unroll
  for (int cb = 0; cb < 4; ++cb) {
#pragma unroll
    for (int reg = 0; reg < 4; ++reg) {
      float v = acc[cb][reg];
      float sv = __builtin_amdgcn_sinf(v);   // reference is sin(2*pi*dot); v_sin takes revolutions
      float cv = __builtin_amdgcn_cosf(v);
      float* po = out + (size_t)(n0 + 4 * h + reg) * 128 + cb * 16 + jc;
      po[0] = sv;
      po[64] = cv;
    }
  }
}

// ---------------- launcher ----------------

extern "C" void kernel_launch(void* const* d_in, const int* in_sizes, int n_in,
                              void* d_out, int out_size, void* d_ws, size_t ws_size,
                              hipStream_t stream) {
  const float* coords = (const float*)d_in[0];
  const float* plane3 = (const float*)d_in[1];
  const float* plane2 = (const float*)d_in[2];
  const float* vec1   = (const float*)d_in[3];
  const float* B      = (const float*)d_in[4];
  float* out = (float*)d_out;
  int N = in_sizes[0] / 3;

  char* ws = (char*)d_ws;
  const size_t off_p3 = 0;
  const size_t off_p2 = off_p3 + (size_t)3 * 128 * 128 * 32;   // fp8 bytes
  const size_t off_vt = off_p2 + (size_t)3 * 256 * 256 * 32;
  const size_t off_bf = off_vt + (size_t)3 * 512 * 32;
  uint8_t* p3t = (uint8_t*)(ws + off_p3);
  uint8_t* p2t = (uint8_t*)(ws + off_p2);
  uint8_t* vt  = (uint8_t*)(ws + off_vt);
  uint4* Bf = (uint4*)(ws + off_bf);

  hipLaunchKernelGGL(make_bfrag, dim3(3), dim3(256), 0, stream, B, Bf);
  hipLaunchKernelGGL(transpose_cl8, dim3(3 * 128 * 2), dim3(256), 0, stream, plane3, p3t, 128, 128, 2, S3);
  hipLaunchKernelGGL(transpose_cl8, dim3(3 * 256 * 4), dim3(256), 0, stream, plane2, p2t, 256, 256, 4, S2);
  hipLaunchKernelGGL(transpose_cl8, dim3(3 * 1 * 8), dim3(256), 0, stream, vec1, vt, 1, 512, 8, SV);
  hipLaunchKernelGGL(triplane_main, dim3((N * 4 + 255) / 256), dim3(256), 0, stream,
                     coords, p3t, p2t, vt, Bf, out, N);
}

// Round 7
// 245.426 us; speedup vs baseline: 3.6657x; 3.6657x over previous
//
#include <hip/hip_runtime.h>
#include <hip/hip_bf16.h>
#include <stdint.h>

typedef float f32x2 __attribute__((ext_vector_type(2)));
typedef float f32x4 __attribute__((ext_vector_type(4)));
typedef short s16x8 __attribute__((ext_vector_type(8)));

#define CUBIC_A (-0.75f)
#define S3 262144.0f   // 2^18 scale for plane3
#define S2 131072.0f   // 2^17 scale for plane2
#define SV 32768.0f    // 2^15 scale for vec

// padded plane geometry (x-axis padded with clamped border texels at both ends)
#define PL3 (128 * 132 * 32)   // per-plane bytes, scale 3 (H=128, Wp=132)
#define PL2 (256 * 260 * 32)   // scale 2 (H=256, Wp=260)
#define PLV (516 * 32)         // vec (Wp=516)
#define STRIDE3 (132 * 32)
#define STRIDE2 (260 * 32)

__device__ __forceinline__ void cubic_w(float t, float* w) {
  float s = t + 1.0f;
  w[0] = ((CUBIC_A * s - 5.0f * CUBIC_A) * s + 8.0f * CUBIC_A) * s - 4.0f * CUBIC_A;
  w[1] = ((CUBIC_A + 2.0f) * t - (CUBIC_A + 3.0f)) * t * t + 1.0f;
  float u = 1.0f - t;
  w[2] = ((CUBIC_A + 2.0f) * u - (CUBIC_A + 3.0f)) * u * u + 1.0f;
  float v = 2.0f - t;
  w[3] = ((CUBIC_A * v - 5.0f * CUBIC_A) * v + 8.0f * CUBIC_A) * v - 4.0f * CUBIC_A;
}

// col-axis: weights + window base byte (padded layout: window start x0-1 -> byte x0*32)
__device__ __forceinline__ void axis_w(float c, int size, float* w, int* colb) {
  float ix = (c + 1.0f) * 0.5f * (float)(size - 1);
  float x0f = floorf(ix);
  cubic_w(ix - x0f, w);
  *colb = (int)x0f * 32;
}

// row-axis: weights + clamped row byte offsets
__device__ __forceinline__ void axis_r(float c, int size, int strideB, float* w, int* ro) {
  float ix = (c + 1.0f) * 0.5f * (float)(size - 1);
  float x0f = floorf(ix);
  cubic_w(ix - x0f, w);
  int x0 = (int)x0f;
#pragma unroll
  for (int k = 0; k < 4; ++k) {
    int qq = x0 - 1 + k;
    qq = qq < 0 ? 0 : qq;
    qq = qq > size - 1 ? size - 1 : qq;
    ro[k] = qq * strideB;
  }
}

// both (y axis is used as rows and cols)
__device__ __forceinline__ void axis_wr(float c, int size, int strideB, float* w, int* colb, int* ro) {
  float ix = (c + 1.0f) * 0.5f * (float)(size - 1);
  float x0f = floorf(ix);
  cubic_w(ix - x0f, w);
  int x0 = (int)x0f;
  *colb = x0 * 32;
#pragma unroll
  for (int k = 0; k < 4; ++k) {
    int qq = x0 - 1 + k;
    qq = qq < 0 ? 0 : qq;
    qq = qq > size - 1 ? size - 1 : qq;
    ro[k] = qq * strideB;
  }
}

// issue 8 x 16B loads: 4 rows x 2 half-windows (lane's q*16 already folded into base)
__device__ __forceinline__ void issueW(const uint8_t* __restrict__ base,
                                       const int* ro, int cb, uint4* r) {
#pragma unroll
  for (int i = 0; i < 4; ++i) {
    r[2 * i]     = *reinterpret_cast<const uint4*>(base + ro[i] + cb);
    r[2 * i + 1] = *reinterpret_cast<const uint4*>(base + ro[i] + cb + 64);
  }
}

// unpack 16 fp8 channels with one weight into acc8 (8 f32x2 = 16 ch)
__device__ __forceinline__ void consume16(uint4 v, float w, f32x2* acc8) {
  f32x2 w2; w2.x = w; w2.y = w;
  acc8[0] += w2 * __builtin_amdgcn_cvt_pk_f32_fp8((int)v.x, false);
  acc8[1] += w2 * __builtin_amdgcn_cvt_pk_f32_fp8((int)v.x, true);
  acc8[2] += w2 * __builtin_amdgcn_cvt_pk_f32_fp8((int)v.y, false);
  acc8[3] += w2 * __builtin_amdgcn_cvt_pk_f32_fp8((int)v.y, true);
  acc8[4] += w2 * __builtin_amdgcn_cvt_pk_f32_fp8((int)v.z, false);
  acc8[5] += w2 * __builtin_amdgcn_cvt_pk_f32_fp8((int)v.z, true);
  acc8[6] += w2 * __builtin_amdgcn_cvt_pk_f32_fp8((int)v.w, false);
  acc8[7] += w2 * __builtin_amdgcn_cvt_pk_f32_fp8((int)v.w, true);
}

// consume one plane sample: 4 rows x {texel p0 (w=wr*cw0), texel p0+2 (w=wr*cw1)}
__device__ __forceinline__ void consumeW(const float* wr, float cw0, float cw1,
                                         const uint4* r, f32x2* acc8) {
#pragma unroll
  for (int i = 0; i < 4; ++i) {
    consume16(r[2 * i],     wr[i] * cw0, acc8);
    consume16(r[2 * i + 1], wr[i] * cw1, acc8);
  }
}

// ---------------- prep kernels ----------------

__device__ __forceinline__ float comb_row(const float* __restrict__ B, int r, int j) {
  return (r < 32) ? (B[r * 64 + j] + B[(r + 32) * 64 + j]) : B[(r + 32) * 64 + j];
}

__device__ __forceinline__ uint32_t pack_bf16(float v0, float v1) {
  uint32_t a = __float_as_uint(v0);
  uint32_t b = __float_as_uint(v1);
  uint32_t r0 = (a + 0x7fffu + ((a >> 16) & 1u)) >> 16;     // RNE
  uint32_t r1 = (b + 0x7fffu + ((b >> 16) & 1u)) >> 16;
  return (r0 & 0xffffu) | (r1 << 16);
}

// Bf[seg=3][cb=4][lane=64] = uint4 (8 bf16, k=(lane>>4)*8+e, j=cb*16+(lane&15)), invS folded
__global__ void __launch_bounds__(256) make_bfrag(const float* __restrict__ B, uint4* __restrict__ Bf) {
  int i = blockIdx.x * 256 + threadIdx.x;
  if (i >= 768) return;
  int lane = i & 63;
  int cb = (i >> 6) & 3;
  int seg = i >> 8;
  float invS = (seg == 0) ? (1.0f / S3) : (seg == 1) ? (1.0f / S2) : (1.0f / SV);
  int j = cb * 16 + (lane & 15);
  int h = lane >> 4;
  uint32_t o[4];
#pragma unroll
  for (int r = 0; r < 4; ++r) {
    int k0 = seg * 32 + h * 8 + 2 * r;
    float v0 = comb_row(B, k0, j) * invS;
    float v1 = comb_row(B, k0 + 1, j) * invS;
    o[r] = pack_bf16(v0, v1);
  }
  uint4 st; st.x = o[0]; st.y = o[1]; st.z = o[2]; st.w = o[3];
  Bf[(seg * 4 + cb) * 64 + lane] = st;
}

// Transpose+quantize (P, 32, H, W) fp32 -> (P, H, Wp, 32) fp8 e4m3 scaled by S,
// with x-padding: texel x stored at slot x+1; slot 0 = texel 0; slots W+1,W+2 = texel W-1.
__global__ void __launch_bounds__(256) transpose_cl8(const float* __restrict__ in,
                                                     uint8_t* __restrict__ out,
                                                     int H, int W, int Wp, int nxt, float S) {
  __shared__ float tile[32][65];
  int b = blockIdx.x;
  int xt = b % nxt;
  int tmp = b / nxt;
  int y = tmp % H;
  int p = tmp / H;
  int x0 = xt * 64;
  int lane = threadIdx.x;
  const float* src = in + ((size_t)p * 32 * (size_t)H) * (size_t)W + (size_t)y * (size_t)W;
  int cx = lane & 63;
  int c4 = lane >> 6;
#pragma unroll
  for (int pass = 0; pass < 8; ++pass) {
    int c = pass * 4 + c4;
    tile[c][cx] = src[(size_t)c * (size_t)(H) * (size_t)W + x0 + cx];
  }
  __syncthreads();
  int xx = lane >> 2;
  int c8 = (lane & 3) * 8;
  float f[8];
#pragma unroll
  for (int i = 0; i < 8; ++i) f[i] = tile[c8 + i][xx] * S;
  uint32_t lo = 0, hi = 0;
  lo = (uint32_t)__builtin_amdgcn_cvt_pk_fp8_f32(f[0], f[1], (int)lo, false);
  lo = (uint32_t)__builtin_amdgcn_cvt_pk_fp8_f32(f[2], f[3], (int)lo, true);
  hi = (uint32_t)__builtin_amdgcn_cvt_pk_fp8_f32(f[4], f[5], (int)hi, false);
  hi = (uint32_t)__builtin_amdgcn_cvt_pk_fp8_f32(f[6], f[7], (int)hi, true);
  uint2 st; st.x = lo; st.y = hi;
  int x = x0 + xx;
  uint8_t* rowb = out + (((size_t)p * H + y) * (size_t)Wp) * 32;
  *reinterpret_cast<uint2*>(rowb + (size_t)(x + 1) * 32 + c8) = st;
  if (x == 0)
    *reinterpret_cast<uint2*>(rowb + c8) = st;
  if (x == W - 1) {
    *reinterpret_cast<uint2*>(rowb + (size_t)(W + 1) * 32 + c8) = st;
    *reinterpret_cast<uint2*>(rowb + (size_t)(W + 2) * 32 + c8) = st;
  }
}

// ---------------- main kernel: window gathers (2x dwordx4 per sample-row), MFMA projection ----------------

__global__ void __launch_bounds__(256, 4) triplane_main(
    const float* __restrict__ coords,
    const uint8_t* __restrict__ p3t,   // (3,128,132,32) fp8, x-padded
    const uint8_t* __restrict__ p2t,   // (3,256,260,32) fp8
    const uint8_t* __restrict__ vt,    // (3,516,32) fp8
    const uint4* __restrict__ Bfrag,   // [3][4][64] uint4
    float* __restrict__ out, int N) {
  int t = blockIdx.x * 256 + threadIdx.x;
  int l = threadIdx.x & 63;
  int n0 = (blockIdx.x * 256 + (threadIdx.x & ~63)) >> 2;  // first point of this wave
  if (n0 >= N) return;
  int n = t >> 2;
  int q = l & 3;
  bool hiq = (q >> 1) != 0;   // texel-pair selector
  int q16 = q * 16;

  float x = coords[3 * n + 0];
  float y = coords[3 * n + 1];
  float z = coords[3 * n + 2];

  f32x2 feat2[24];   // [seg=3][8]: entry e = channels {2e,2e+1} of this lane's 16-ch half
#pragma unroll
  for (int i = 0; i < 24; ++i) { feat2[i].x = 0.f; feat2[i].y = 0.f; }

  uint4 rA[8], rB[8];

  // ======== scale 3 (H=128) ========
  float wx[4], wy[4], wz[4];
  int cbx, cby, roy[4], roz[4];
  axis_w(x, 128, wx, &cbx);
  axis_wr(y, 128, STRIDE3, wy, &cby, roy);
  axis_r(z, 128, STRIDE3, wz, roz);
  float cx0 = hiq ? wx[1] : wx[0], cx1 = hiq ? wx[3] : wx[2];
  float cy0 = hiq ? wy[1] : wy[0], cy1 = hiq ? wy[3] : wy[2];

  const uint8_t* b3 = p3t + q16;
  issueW(b3,           roy, cbx, rA);   // xy: rows y, cols x
  issueW(b3 + 1 * PL3, roz, cby, rB);   // yz: rows z, cols y
  consumeW(wy, cx0, cx1, rA, feat2 + 0);
  issueW(b3 + 2 * PL3, roz, cbx, rA);   // xz: rows z, cols x
  consumeW(wz, cy0, cy1, rB, feat2 + 0);

  // ======== scale 2 (H=256) ========
  float wx2[4], wy2[4], wz2[4];
  int cbx2, cby2, roy2[4], roz2[4];
  axis_w(x, 256, wx2, &cbx2);
  axis_wr(y, 256, STRIDE2, wy2, &cby2, roy2);
  axis_r(z, 256, STRIDE2, wz2, roz2);
  float cx20 = hiq ? wx2[1] : wx2[0], cx21 = hiq ? wx2[3] : wx2[2];
  float cy20 = hiq ? wy2[1] : wy2[0], cy21 = hiq ? wy2[3] : wy2[2];

  const uint8_t* b2 = p2t + q16;
  issueW(b2,           roy2, cbx2, rB);               // p2 xy
  consumeW(wz, cx0, cx1, rA, feat2 + 0);              // p3 xz
  issueW(b2 + 1 * PL2, roz2, cby2, rA);               // p2 yz
  consumeW(wy2, cx20, cx21, rB, feat2 + 8);           // p2 xy
  issueW(b2 + 2 * PL2, roz2, cbx2, rB);               // p2 xz
  consumeW(wz2, cy20, cy21, rA, feat2 + 8);           // p2 yz

  // ======== vector (W=512) ========
  float wvx[4], wvy[4], wvz[4];
  int cbvx, cbvy, cbvz;
  axis_w(x, 512, wvx, &cbvx);
  axis_w(y, 512, wvy, &cbvy);
  axis_w(z, 512, wvz, &cbvz);
  {
    const uint8_t* v0 = vt + q16;
    rA[0] = *reinterpret_cast<const uint4*>(v0 + cbvx);
    rA[1] = *reinterpret_cast<const uint4*>(v0 + cbvx + 64);
    rA[2] = *reinterpret_cast<const uint4*>(v0 + PLV + cbvy);
    rA[3] = *reinterpret_cast<const uint4*>(v0 + PLV + cbvy + 64);
    rA[4] = *reinterpret_cast<const uint4*>(v0 + 2 * PLV + cbvz);
    rA[5] = *reinterpret_cast<const uint4*>(v0 + 2 * PLV + cbvz + 64);
  }
  consumeW(wz2, cx20, cx21, rB, feat2 + 8);           // p2 xz
  {
    float a0 = hiq ? wvx[1] : wvx[0], a1 = hiq ? wvx[3] : wvx[2];
    float b0 = hiq ? wvy[1] : wvy[0], b1 = hiq ? wvy[3] : wvy[2];
    float c0 = hiq ? wvz[1] : wvz[0], c1 = hiq ? wvz[3] : wvz[2];
    consume16(rA[0], a0, feat2 + 16);
    consume16(rA[1], a1, feat2 + 16);
    consume16(rA[2], b0, feat2 + 16);
    consume16(rA[3], b1, feat2 + 16);
    consume16(rA[4], c0, feat2 + 16);
    consume16(rA[5], c1, feat2 + 16);
  }

  // ---- pair-reduce (lane q with lane q^2) + pack own k-quarter to bf16 ----
  // lane q owns quarter qq = ((q&1)<<1)|(q>>1): half q&1, channel offset 8*(q>>1)
  uint32_t packed[12];
#pragma unroll
  for (int s = 0; s < 3; ++s) {
#pragma unroll
    for (int r = 0; r < 4; ++r) {
      f32x2 lo = feat2[s * 8 + r];
      f32x2 hi = feat2[s * 8 + 4 + r];
      float ownx = hiq ? hi.x : lo.x, owny = hiq ? hi.y : lo.y;
      float sndx = hiq ? lo.x : hi.x, sndy = hiq ? lo.y : hi.y;
      float rx = ownx + __shfl_xor(sndx, 2);
      float ry = owny + __shfl_xor(sndy, 2);
      uint32_t pk;
      asm("v_cvt_pk_bf16_f32 %0, %1, %2" : "=v"(pk) : "v"(rx), "v"(ry));
      packed[s * 4 + r] = pk;
    }
  }

  // ---- redistribute to MFMA A-fragment: dest lane 16h'+p pulls quarter h' of point p.
  // quarter h' lives in lane 4p + ((h'&1)<<1 | h'>>1)
  int hp = l >> 4;
  int srcq = ((hp & 1) << 1) | (hp >> 1);
  int baddr = (4 * (l & 15) + srcq) * 4;
  uint32_t apk[12];
#pragma unroll
  for (int i = 0; i < 12; ++i)
    apk[i] = (uint32_t)__builtin_amdgcn_ds_bpermute(baddr, (int)packed[i]);

  // ---- load B fragments ----
  uint4 bfr[12];
#pragma unroll
  for (int i = 0; i < 12; ++i) bfr[i] = Bfrag[i * 64 + l];

  // ---- 12 MFMAs ----
  union U { uint32_t u[4]; s16x8 v; };
  f32x4 acc[4];
#pragma unroll
  for (int cb = 0; cb < 4; ++cb) { acc[cb].x = 0.f; acc[cb].y = 0.f; acc[cb].z = 0.f; acc[cb].w = 0.f; }
#pragma unroll
  for (int seg = 0; seg < 3; ++seg) {
    U a;
    a.u[0] = apk[seg * 4 + 0];
    a.u[1] = apk[seg * 4 + 1];
    a.u[2] = apk[seg * 4 + 2];
    a.u[3] = apk[seg * 4 + 3];
#pragma unroll
    for (int cb = 0; cb < 4; ++cb) {
      U b;
      b.u[0] = bfr[seg * 4 + cb].x;
      b.u[1] = bfr[seg * 4 + cb].y;
      b.u[2] = bfr[seg * 4 + cb].z;
      b.u[3] = bfr[seg * 4 + cb].w;
      acc[cb] = __builtin_amdgcn_mfma_f32_16x16x32_bf16(a.v, b.v, acc[cb], 0, 0, 0);
    }
  }

  // ---- epilogue: sin/cos + store. C/D: row (=point) = (l>>4)*4+reg, col = l&15 ----
  int jc = l & 15;
#pragma unroll
  for (int cb = 0; cb < 4; ++cb) {
#pragma unroll
    for (int reg = 0; reg < 4; ++reg) {
      float v = acc[cb][reg];
      float sv = __builtin_amdgcn_sinf(v);   // reference is sin(2*pi*dot); v_sin takes revolutions
      float cv = __builtin_amdgcn_cosf(v);
      float* po = out + (size_t)(n0 + 4 * hp + reg) * 128 + cb * 16 + jc;
      po[0] = sv;
      po[64] = cv;
    }
  }
}

// ---------------- launcher ----------------

extern "C" void kernel_launch(void* const* d_in, const int* in_sizes, int n_in,
                              void* d_out, int out_size, void* d_ws, size_t ws_size,
                              hipStream_t stream) {
  const float* coords = (const float*)d_in[0];
  const float* plane3 = (const float*)d_in[1];
  const float* plane2 = (const float*)d_in[2];
  const float* vec1   = (const float*)d_in[3];
  const float* B      = (const float*)d_in[4];
  float* out = (float*)d_out;
  int N = in_sizes[0] / 3;

  char* ws = (char*)d_ws;
  const size_t off_p3 = 0;
  const size_t off_p2 = off_p3 + (size_t)3 * PL3;   // 1,622,016
  const size_t off_vt = off_p2 + (size_t)3 * PL2;   // +6,389,760
  const size_t off_bf = off_vt + (size_t)3 * PLV;   // +49,536
  uint8_t* p3t = (uint8_t*)(ws + off_p3);
  uint8_t* p2t = (uint8_t*)(ws + off_p2);
  uint8_t* vt  = (uint8_t*)(ws + off_vt);
  uint4* Bf = (uint4*)(ws + off_bf);

  hipLaunchKernelGGL(make_bfrag, dim3(3), dim3(256), 0, stream, B, Bf);
  hipLaunchKernelGGL(transpose_cl8, dim3(3 * 128 * 2), dim3(256), 0, stream, plane3, p3t, 128, 128, 132, 2, S3);
  hipLaunchKernelGGL(transpose_cl8, dim3(3 * 256 * 4), dim3(256), 0, stream, plane2, p2t, 256, 256, 260, 4, S2);
  hipLaunchKernelGGL(transpose_cl8, dim3(3 * 1 * 8), dim3(256), 0, stream, vec1, vt, 1, 512, 516, 8, SV);
  hipLaunchKernelGGL(triplane_main, dim3((N * 4 + 255) / 256), dim3(256), 0, stream,
                     coords, p3t, p2t, vt, Bf, out, N);
}